// Round 3
// baseline (375.744 us; speedup 1.0000x reference)
//
#include <hip/hip_runtime.h>
#include <hip/hip_bf16.h>

// ConvSelfAttentionModule: B=4, C=256, CQK=128, N=4096 (64x64), fp32 in/out.
// R11: register-direct flash attention with FRAGMENT-TILED global layouts.
// R2 lesson: register-direct frag loads from row-major qk/vv are 16-way
// scatters (512B-8KB lane strides) -> VMEM-bound (MfmaUtil 15%). Fix: k_proj
// writes Q/K/V in MFMA fragment-tile order (each 16x32 tile = 1KB contiguous,
// lane-major), so every consumer fragment load is ONE coalesced 1KB
// global_load_dwordx4. No LDS staging anywhere in the attention kernels;
// only E (cross-wave j<->i exchange) lives in LDS (16KB dbuf, 1 lgkm-only
// barrier/iter — verified-safe structure from R2).
//   k_wcvt   : W -> f16
//   k_xsplit : transpose x[b][c][n] -> xT[b][n][c] f16
//   k_proj   : f16 MFMA GEMM -> qT/kT/vT in fragment-tiled layout
//              qT/kT[b][t16][kt4][quad4][col16][e8], vT[b][ct16][it128][...]
//   k_rows   : QK^T + exp + partial row sums, register-direct, no LDS/barrier
//   k_rsum   : rinv[b][i] = 1 / sum_j exp(S[i,j])
//   k_fav    : fused recompute+AV, register-direct, sE dbuf only

typedef _Float16 f16;
typedef _Float16 f16x4v __attribute__((ext_vector_type(4)));
typedef _Float16 f16x8v __attribute__((ext_vector_type(8)));
typedef float f32x4v __attribute__((ext_vector_type(4)));

static __device__ __forceinline__ f32x4v mfma16(f16x8v a, f16x8v b, f32x4v c) {
  // A-frag m=lane&15,k=quad*8+e; B-frag n=lane&15,k=quad*8+e
  // D: col(n)=lane&15, row(m)=quad*4+reg
  return __builtin_amdgcn_mfma_f32_16x16x32_f16(a, b, c, 0, 0, 0);
}

#define AS1q __attribute__((address_space(1)))
#define AS3q __attribute__((address_space(3)))
static __device__ __forceinline__ void gl_lds16(const void* g, void* l) {
  __builtin_amdgcn_global_load_lds((const AS1q unsigned int*)g,
                                   (AS3q unsigned int*)l, 16, 0, 0);
}

// ---------------- kernel 0a: weight convert ----------------
__global__ void k_wcvt(const float* __restrict__ wq, const float* __restrict__ bq,
                       const float* __restrict__ wk, const float* __restrict__ bk,
                       const float* __restrict__ wv, const float* __restrict__ bv,
                       f16* __restrict__ wh, float* __restrict__ bcat) {
  int o = blockIdx.x;          // 512 rows: 0-127 q, 128-255 k, 256-511 v
  int c = threadIdx.x;         // 256
  const float* wrow; float bias;
  if (o < 128)      { wrow = wq + (size_t)o * 256;         bias = bq[o]; }
  else if (o < 256) { wrow = wk + (size_t)(o - 128) * 256; bias = bk[o - 128]; }
  else              { wrow = wv + (size_t)(o - 256) * 256; bias = bv[o - 256]; }
  wh[(size_t)o * 256 + c] = (f16)wrow[c];
  if (c == 0) bcat[o] = bias;
}

// ---------------- kernel 0b: x transpose ----------------
__global__ void k_xsplit(const float* __restrict__ x, f16* __restrict__ xh) {
  __shared__ float t[64][65];
  int b = blockIdx.z, c0 = blockIdx.y * 64, n0 = blockIdx.x * 64;
  int tx = threadIdx.x & 63, ty = threadIdx.x >> 6;
  const float* xb = x + ((size_t)b * 256 + c0) * 4096 + n0;
#pragma unroll
  for (int r = ty; r < 64; r += 4) t[r][tx] = xb[(size_t)r * 4096 + tx];
  __syncthreads();
  f16* dh = xh + ((size_t)b * 4096 + n0) * 256 + c0;
#pragma unroll
  for (int r = ty; r < 64; r += 4)
    dh[(size_t)r * 256 + tx] = (f16)t[tx][r];
}

// ---------------- kernel 1: projections -> fragment-tiled outputs ----------------
// GEMM part unchanged from R1/R2 (verified). Epilogue writes tiled layouts:
//  qT/kT elem addr = b*524288 + t*2048 + kt*512 + qd*128 + (row&15)*8 + e
//    (t = token>>4, d=channel: kt=d>>5, qd=(d>>3)&3, e=d&7)
//  vT   elem addr = b*1048576 + ct*65536 + it2*512 + qd2*128 + (c&15)*8 + e2
//    (ct=c>>4, i: it2=i>>5, qd2=(i>>3)&3, e2=i&7)
__global__ void __launch_bounds__(256, 2)
k_proj(const f16* __restrict__ xh, const f16* __restrict__ wh,
       const float* __restrict__ bcat, f16* __restrict__ qT,
       f16* __restrict__ kT, f16* __restrict__ vT) {
  extern __shared__ char smem[];   // 64KB
  int b = blockIdx.z, m0 = blockIdx.y * 64, n0 = blockIdx.x * 64;
  int tid = threadIdx.x, l = tid & 63, w = tid >> 6;
  int col = l & 15, quad = l >> 4;
  const f16* Ag = xh + ((size_t)b * 4096 + m0) * 256;
  const f16* Wg = wh + (size_t)n0 * 256;
  int rloc = l >> 5;
  int l5 = l & 31;
#pragma unroll
  for (int p = 0; p < 8; p++) {
    int ci = w * 8 + p;
    int r = ci * 2 + rloc;
    int g = l5 ^ (r & 31);
    gl_lds16(Ag + (size_t)r * 256 + g * 8, smem + ci * 1024);
    gl_lds16(Wg + (size_t)r * 256 + g * 8, smem + 32768 + ci * 1024);
  }
  __syncthreads();
  const char* sA = smem;
  const char* sW = smem + 32768;
  f32x4v acc[4] = {};
  int ar = w * 16 + col;
#pragma unroll
  for (int ks = 0; ks < 8; ks++) {
    int G = ks * 4 + quad;
    f16x8v a = *(const f16x8v*)(sA + ar * 512 + ((G ^ (ar & 31)) * 16));
#pragma unroll
    for (int nt = 0; nt < 4; nt++) {
      int wr = nt * 16 + col;
      f16x8v bb = *(const f16x8v*)(sW + wr * 512 + ((G ^ (wr & 31)) * 16));
      acc[nt] = mfma16(a, bb, acc[nt]);
    }
  }
  if (n0 < 256) {   // q or k rows (block-uniform per nt set? n0 in {0,64,128,192})
#pragma unroll
    for (int nt = 0; nt < 4; nt++) {
      int o = n0 + nt * 16 + col;
      float bias = bcat[o];
      int d = o & 127;
      f16* dst = (o < 128) ? qT : kT;
      size_t tb = (size_t)b * 524288 + (size_t)(m0 / 16 + w) * 2048 +
                  (size_t)(d >> 5) * 512 + (size_t)((d >> 3) & 3) * 128 + (d & 7);
#pragma unroll
      for (int rg = 0; rg < 4; rg++)
        dst[tb + (quad * 4 + rg) * 8] = (f16)(acc[nt][rg] + bias);
    }
  } else {
    int i2 = w * 16 + quad * 4;              // token offset within m0 block
    int it2 = (m0 + i2) >> 5;
    int qd2 = (i2 >> 3) & 3;
    int e2 = i2 & 7;                          // 0 or 4; rg appends
#pragma unroll
    for (int nt = 0; nt < 4; nt++) {
      int o = n0 + nt * 16 + col;
      float bias = bcat[o];
      int c = o - 256;
      f16x4v pv;
#pragma unroll
      for (int rg = 0; rg < 4; rg++) pv[rg] = (f16)(acc[nt][rg] + bias);
      size_t addr = (size_t)b * 1048576 + (size_t)(c >> 4) * 65536 +
                    (size_t)it2 * 512 + (size_t)qd2 * 128 + (size_t)(c & 15) * 8 + e2;
      *(f16x4v*)&vT[addr] = pv;
    }
  }
}

// ---------------- kernel 2: row sums of exp(S), register-direct tiled ----------------
// wg = (jblk, ih, b), 512 thr. Wave (ti=w&3, half=w>>2): K j-tile pair
// (tjb=half*2) resident in regs; loops 32 i-iters (i-tile = it*4+ti),
// Q frags dbuf-prefetched; exp + in-wave j-reduction.
// partial[b][jblk*2+half][i] = sum over 32 j of exp(s_ij). No LDS/barriers.
__global__ void __launch_bounds__(512, 4)
k_rows(const f16* __restrict__ qT, const f16* __restrict__ kT,
       float* __restrict__ partial) {
  int jblk = blockIdx.x, ih = blockIdx.y, b = blockIdx.z;
  int tid = threadIdx.x, l = tid & 63, w = tid >> 6;
  int col = l & 15;
  int ti = w & 3, half = w >> 2, tjb = half * 2;
  const f16* ktb = kT + (size_t)b * 524288 + (size_t)(jblk * 4 + tjb) * 2048 + l * 8;
  const f16* qtb = qT + (size_t)b * 524288 + (size_t)ti * 2048 + l * 8;
  f16x8v ka0[4], ka1[4];
#pragma unroll
  for (int ks = 0; ks < 4; ks++) {
    ka0[ks] = *(const f16x8v*)(ktb + ks * 512);
    ka1[ks] = *(const f16x8v*)(ktb + 2048 + ks * 512);
  }
  float* pout = partial + ((size_t)(b * 64 + jblk) * 2 + half) * 4096 + ti * 16 + col;
  int it0 = ih * 32;
  f16x8v qfA[4], qfB[4];
#pragma unroll
  for (int ks = 0; ks < 4; ks++)
    qfA[ks] = *(const f16x8v*)(qtb + (size_t)it0 * 8192 + ks * 512);

#define ROWS_BODY(IT, QF, QN, PREF)                                           \
  {                                                                           \
    if (PREF) {                                                               \
      _Pragma("unroll") for (int ks = 0; ks < 4; ks++)                        \
        QN[ks] = *(const f16x8v*)(qtb + (size_t)((IT) + 1) * 8192 + ks * 512);\
    }                                                                         \
    f32x4v s0 = {}, s1 = {};                                                  \
    _Pragma("unroll") for (int ks = 0; ks < 4; ks++) {                        \
      s0 = mfma16(ka0[ks], QF[ks], s0);                                       \
      s1 = mfma16(ka1[ks], QF[ks], s1);                                       \
    }                                                                         \
    float t = 0.f;                                                            \
    _Pragma("unroll") for (int rg = 0; rg < 4; rg++)                          \
      t += __expf(s0[rg]) + __expf(s1[rg]);                                   \
    t += __shfl_xor(t, 16);                                                   \
    t += __shfl_xor(t, 32);                                                   \
    if (l < 16) pout[(size_t)(IT) * 64] = t;                                  \
  }

  for (int itp = 0; itp < 16; itp++) {
    int itA = it0 + itp * 2;
    ROWS_BODY(itA, qfA, qfB, true)
    ROWS_BODY(itA + 1, qfB, qfA, itp < 15)
  }
#undef ROWS_BODY
}

// ---------------- kernel 3: combine partials -> rinv = 1/rowsum ----------------
__global__ void k_rsum(const float* __restrict__ partial, float* __restrict__ rinv) {
  int b = blockIdx.y;
  int i = blockIdx.x * 256 + threadIdx.x;
  const float* p = partial + (size_t)b * 128 * 4096 + i;
  float s = 0.f;
#pragma unroll 8
  for (int jb = 0; jb < 128; jb++) s += p[(size_t)jb * 4096];
  rinv[(size_t)b * 4096 + i] = 1.0f / s;
}

// ---------------- kernel 4: fused recompute + AV, register-direct tiled ----------------
// Per wg: batch b, j-cols [j0,j0+64), all 256 c. Loop i in 64-steps:
//   S^T = mfma(K_regs, Q_regs);  E' = exp(S)*rinv -> sE (dbuf, swizzled)
//   acc[c][j] += mfma(V_regs, E'^T)
// All frag loads = coalesced 1KB from tiled layouts, prefetched 1 tile ahead.
// One lgkm-only s_barrier per iter (sE dbuf makes WAR safe — R2-verified).
__global__ void __launch_bounds__(512, 4)
k_fav(const f16* __restrict__ qT, const f16* __restrict__ kT,
      const f16* __restrict__ vT, const float* __restrict__ rinv,
      const float* __restrict__ x, const float* __restrict__ gamma,
      float* __restrict__ out) {
  __shared__ f16 sE[2][4096];   // [buf][64 j][64 i], 8-elem groups XOR(j&7)
  // XCD-chunked swizzle: 256 wgs, 8 XCDs -> contiguous 32-wg slice per XCD.
  int wg = blockIdx.x;
  int lg = (wg & 7) * 32 + (wg >> 3);
  int b = lg >> 6, j0 = (lg & 63) * 64;
  int tid = threadIdx.x, l = tid & 63, w = tid >> 6;
  int col = l & 15, quad = l >> 4;
  int ti = w & 3, tjb = (w >> 2) * 2;
  const f16* ktb = kT + (size_t)b * 524288 + (size_t)(j0 / 16 + tjb) * 2048 + l * 8;
  const f16* qtb = qT + (size_t)b * 524288 + (size_t)ti * 2048 + l * 8;
  const f16* vtb = vT + (size_t)b * 1048576 + (size_t)(w * 2) * 65536 + l * 8;
  const float* rp = rinv + (size_t)b * 4096 + ti * 16 + col;
  // K fragments: resident whole kernel
  f16x8v ka0[4], ka1[4];
#pragma unroll
  for (int ks = 0; ks < 4; ks++) {
    ka0[ks] = *(const f16x8v*)(ktb + ks * 512);
    ka1[ks] = *(const f16x8v*)(ktb + 2048 + ks * 512);
  }
  f16x8v qfA[4], qfB[4], vfA[2][2], vfB[2][2];
  float rvA, rvB;
#pragma unroll
  for (int ks = 0; ks < 4; ks++) qfA[ks] = *(const f16x8v*)(qtb + ks * 512);
#pragma unroll
  for (int mt = 0; mt < 2; mt++)
#pragma unroll
    for (int ks = 0; ks < 2; ks++)
      vfA[mt][ks] = *(const f16x8v*)(vtb + mt * 65536 + ks * 512);
  rvA = rp[0];
  f32x4v acc[2][4] = {};
  int ig = ti * 2 + (col >> 3);
  int i_lo = col & 7;

#define FAV_BODY(IT, QF, VF, RV, QN, VN, RN, PREF, SEB)                        \
  {                                                                            \
    if (PREF) {                                                                \
      _Pragma("unroll") for (int ks = 0; ks < 4; ks++)                         \
        QN[ks] = *(const f16x8v*)(qtb + (size_t)((IT) + 1) * 8192 + ks * 512); \
      _Pragma("unroll") for (int mt = 0; mt < 2; mt++)                         \
        _Pragma("unroll") for (int ks = 0; ks < 2; ks++)                       \
          VN[mt][ks] = *(const f16x8v*)(vtb + mt * 65536 +                     \
                                        (size_t)(((IT) + 1) * 2 + ks) * 512);  \
      RN = rp[((IT) + 1) * 64];                                                \
    }                                                                          \
    f32x4v s0 = {}, s1 = {};                                                   \
    _Pragma("unroll") for (int ks = 0; ks < 4; ks++) {                         \
      s0 = mfma16(ka0[ks], QF[ks], s0);                                        \
      s1 = mfma16(ka1[ks], QF[ks], s1);                                        \
    }                                                                          \
    _Pragma("unroll") for (int rg = 0; rg < 4; rg++) {                         \
      int jl0 = tjb * 16 + quad * 4 + rg;                                      \
      sE[SEB][jl0 * 64 + ((ig ^ (jl0 & 7)) * 8) + i_lo] = (f16)(__expf(s0[rg]) * RV); \
      sE[SEB][(jl0 + 16) * 64 + ((ig ^ (jl0 & 7)) * 8) + i_lo] = (f16)(__expf(s1[rg]) * RV); \
    }                                                                          \
    asm volatile("s_waitcnt lgkmcnt(0)\n\ts_barrier" ::: "memory");            \
    _Pragma("unroll") for (int ks = 0; ks < 2; ks++) {                         \
      int sw = ((ks * 4 + quad) ^ (col & 7)) * 8;                              \
      f16x8v e0 = *(const f16x8v*)&sE[SEB][col * 64 + sw];                     \
      f16x8v e1 = *(const f16x8v*)&sE[SEB][(16 + col) * 64 + sw];              \
      f16x8v e2 = *(const f16x8v*)&sE[SEB][(32 + col) * 64 + sw];              \
      f16x8v e3 = *(const f16x8v*)&sE[SEB][(48 + col) * 64 + sw];              \
      acc[0][0] = mfma16(VF[0][ks], e0, acc[0][0]);                            \
      acc[0][1] = mfma16(VF[0][ks], e1, acc[0][1]);                            \
      acc[0][2] = mfma16(VF[0][ks], e2, acc[0][2]);                            \
      acc[0][3] = mfma16(VF[0][ks], e3, acc[0][3]);                            \
      acc[1][0] = mfma16(VF[1][ks], e0, acc[1][0]);                            \
      acc[1][1] = mfma16(VF[1][ks], e1, acc[1][1]);                            \
      acc[1][2] = mfma16(VF[1][ks], e2, acc[1][2]);                            \
      acc[1][3] = mfma16(VF[1][ks], e3, acc[1][3]);                            \
    }                                                                          \
  }

  for (int itp = 0; itp < 32; itp++) {
    int itA = itp * 2;
    FAV_BODY(itA, qfA, vfA, rvA, qfB, vfB, rvB, true, 0)
    FAV_BODY(itA + 1, qfB, vfB, rvB, qfA, vfA, rvA, itp < 31, 1)
  }
#undef FAV_BODY

  float gm = gamma[0];
  const float* xb = x + (size_t)b * 256 * 4096;
  float* ob = out + (size_t)b * 256 * 4096;
#pragma unroll
  for (int mt = 0; mt < 2; mt++)
#pragma unroll
    for (int jt = 0; jt < 4; jt++) {
      int c = w * 32 + mt * 16 + quad * 4;
      int j = j0 + jt * 16 + col;
#pragma unroll
      for (int rg = 0; rg < 4; rg++) {
        size_t off = (size_t)(c + rg) * 4096 + j;
        ob[off] = gm * acc[mt][jt][rg] + xb[off];
      }
    }
}

extern "C" void kernel_launch(void* const* d_in, const int* in_sizes, int n_in,
                              void* d_out, int out_size, void* d_ws, size_t ws_size,
                              hipStream_t stream) {
  (void)in_sizes; (void)n_in; (void)out_size; (void)ws_size;
  const float* x  = (const float*)d_in[0];
  const float* wq = (const float*)d_in[1];
  const float* bq = (const float*)d_in[2];
  const float* wk = (const float*)d_in[3];
  const float* bk = (const float*)d_in[4];
  const float* wv = (const float*)d_in[5];
  const float* bv = (const float*)d_in[6];
  const float* gm = (const float*)d_in[7];
  float* out = (float*)d_out;

  char* ws = (char*)d_ws;
  f16*  xh = (f16*)ws;                          // 8 MB
  f16*  qT = (f16*)(ws + 8388608);              // 4 MB fragment-tiled Q
  f16*  kT = (f16*)(ws + 12582912);             // 4 MB fragment-tiled K
  f16*  vT = (f16*)(ws + 16777216);             // 8 MB fragment-tiled V
  f16*  wh = (f16*)(ws + 25165824);             // 256 KB
  float* bcat    = (float*)(ws + 25427968);     // 2 KB
  float* rinv    = (float*)(ws + 25430016);     // 64 KB
  float* partial = (float*)(ws + 25495552);     // 8 MB: [b][128][4096]

  hipLaunchKernelGGL(k_wcvt, dim3(512), dim3(256), 0, stream, wq, bq, wk, bk, wv, bv, wh, bcat);
  hipLaunchKernelGGL(k_xsplit, dim3(64, 4, 4), dim3(256), 0, stream, x, xh);
  hipLaunchKernelGGL(k_proj, dim3(8, 64, 4), dim3(256), 65536, stream, xh, wh, bcat, qT, kT, vT);
  hipLaunchKernelGGL(k_rows, dim3(64, 2, 4), dim3(512), 0, stream, qT, kT, partial);
  hipLaunchKernelGGL(k_rsum, dim3(16, 4), dim3(256), 0, stream, partial, rinv);
  hipLaunchKernelGGL(k_fav, dim3(256), dim3(512), 0, stream, qT, kT, vT, rinv, x, gm, out);
}

// Round 4
// 191.119 us; speedup vs baseline: 1.9660x; 1.9660x over previous
//
#include <hip/hip_runtime.h>
#include <hip/hip_bf16.h>

// ConvSelfAttentionModule: B=4, C=256, CQK=128, N=4096 (64x64), fp32 in/out.
// R12 = R11 with the register-spill fixed. R3 lesson: __launch_bounds__(512,4)
// caps the allocator at 64 VGPRs on this toolchain -> k_fav (needs ~100)
// spilled every fragment to scratch (WRITE_SIZE 16->422 MB, 253 us). Layout
// was never the problem. This round: identical structure, launch bounds
// reverted to the proven (512,2) [R1/R2 ran 68/80 VGPR spill-free under it].
//   k_wcvt   : W -> f16
//   k_xsplit : transpose x[b][c][n] -> xT[b][n][c] f16
//   k_proj   : f16 MFMA GEMM -> qT/kT/vT in fragment-tiled layout
//              (each 16x32 frag tile = 1KB contiguous, lane-major ->
//               every consumer fragment load is ONE coalesced dwordx4)
//   k_rows   : QK^T + exp + partial row sums, register-direct, no LDS/barrier
//   k_rsum   : rinv[b][i] = 1 / sum_j exp(S[i,j])
//   k_fav    : fused recompute+AV, register-direct, sE 16KB dbuf only,
//              one lgkm-only barrier/iter (R2-verified safe)

typedef _Float16 f16;
typedef _Float16 f16x4v __attribute__((ext_vector_type(4)));
typedef _Float16 f16x8v __attribute__((ext_vector_type(8)));
typedef float f32x4v __attribute__((ext_vector_type(4)));

static __device__ __forceinline__ f32x4v mfma16(f16x8v a, f16x8v b, f32x4v c) {
  // A-frag m=lane&15,k=quad*8+e; B-frag n=lane&15,k=quad*8+e
  // D: col(n)=lane&15, row(m)=quad*4+reg
  return __builtin_amdgcn_mfma_f32_16x16x32_f16(a, b, c, 0, 0, 0);
}

#define AS1q __attribute__((address_space(1)))
#define AS3q __attribute__((address_space(3)))
static __device__ __forceinline__ void gl_lds16(const void* g, void* l) {
  __builtin_amdgcn_global_load_lds((const AS1q unsigned int*)g,
                                   (AS3q unsigned int*)l, 16, 0, 0);
}

// ---------------- kernel 0a: weight convert ----------------
__global__ void k_wcvt(const float* __restrict__ wq, const float* __restrict__ bq,
                       const float* __restrict__ wk, const float* __restrict__ bk,
                       const float* __restrict__ wv, const float* __restrict__ bv,
                       f16* __restrict__ wh, float* __restrict__ bcat) {
  int o = blockIdx.x;          // 512 rows: 0-127 q, 128-255 k, 256-511 v
  int c = threadIdx.x;         // 256
  const float* wrow; float bias;
  if (o < 128)      { wrow = wq + (size_t)o * 256;         bias = bq[o]; }
  else if (o < 256) { wrow = wk + (size_t)(o - 128) * 256; bias = bk[o - 128]; }
  else              { wrow = wv + (size_t)(o - 256) * 256; bias = bv[o - 256]; }
  wh[(size_t)o * 256 + c] = (f16)wrow[c];
  if (c == 0) bcat[o] = bias;
}

// ---------------- kernel 0b: x transpose ----------------
__global__ void k_xsplit(const float* __restrict__ x, f16* __restrict__ xh) {
  __shared__ float t[64][65];
  int b = blockIdx.z, c0 = blockIdx.y * 64, n0 = blockIdx.x * 64;
  int tx = threadIdx.x & 63, ty = threadIdx.x >> 6;
  const float* xb = x + ((size_t)b * 256 + c0) * 4096 + n0;
#pragma unroll
  for (int r = ty; r < 64; r += 4) t[r][tx] = xb[(size_t)r * 4096 + tx];
  __syncthreads();
  f16* dh = xh + ((size_t)b * 4096 + n0) * 256 + c0;
#pragma unroll
  for (int r = ty; r < 64; r += 4)
    dh[(size_t)r * 256 + tx] = (f16)t[tx][r];
}

// ---------------- kernel 1: projections -> fragment-tiled outputs ----------------
//  qT/kT elem addr = b*524288 + t*2048 + kt*512 + qd*128 + (row&15)*8 + e
//    (t = token>>4, d=channel: kt=d>>5, qd=(d>>3)&3, e=d&7)
//  vT   elem addr = b*1048576 + ct*65536 + it2*512 + qd2*128 + (c&15)*8 + e2
//    (ct=c>>4, i: it2=i>>5, qd2=(i>>3)&3, e2=i&7)
__global__ void __launch_bounds__(256, 2)
k_proj(const f16* __restrict__ xh, const f16* __restrict__ wh,
       const float* __restrict__ bcat, f16* __restrict__ qT,
       f16* __restrict__ kT, f16* __restrict__ vT) {
  extern __shared__ char smem[];   // 64KB
  int b = blockIdx.z, m0 = blockIdx.y * 64, n0 = blockIdx.x * 64;
  int tid = threadIdx.x, l = tid & 63, w = tid >> 6;
  int col = l & 15, quad = l >> 4;
  const f16* Ag = xh + ((size_t)b * 4096 + m0) * 256;
  const f16* Wg = wh + (size_t)n0 * 256;
  int rloc = l >> 5;
  int l5 = l & 31;
#pragma unroll
  for (int p = 0; p < 8; p++) {
    int ci = w * 8 + p;
    int r = ci * 2 + rloc;
    int g = l5 ^ (r & 31);
    gl_lds16(Ag + (size_t)r * 256 + g * 8, smem + ci * 1024);
    gl_lds16(Wg + (size_t)r * 256 + g * 8, smem + 32768 + ci * 1024);
  }
  __syncthreads();
  const char* sA = smem;
  const char* sW = smem + 32768;
  f32x4v acc[4] = {};
  int ar = w * 16 + col;
#pragma unroll
  for (int ks = 0; ks < 8; ks++) {
    int G = ks * 4 + quad;
    f16x8v a = *(const f16x8v*)(sA + ar * 512 + ((G ^ (ar & 31)) * 16));
#pragma unroll
    for (int nt = 0; nt < 4; nt++) {
      int wr = nt * 16 + col;
      f16x8v bb = *(const f16x8v*)(sW + wr * 512 + ((G ^ (wr & 31)) * 16));
      acc[nt] = mfma16(a, bb, acc[nt]);
    }
  }
  if (n0 < 256) {
#pragma unroll
    for (int nt = 0; nt < 4; nt++) {
      int o = n0 + nt * 16 + col;
      float bias = bcat[o];
      int d = o & 127;
      f16* dst = (o < 128) ? qT : kT;
      size_t tb = (size_t)b * 524288 + (size_t)(m0 / 16 + w) * 2048 +
                  (size_t)(d >> 5) * 512 + (size_t)((d >> 3) & 3) * 128 + (d & 7);
#pragma unroll
      for (int rg = 0; rg < 4; rg++)
        dst[tb + (quad * 4 + rg) * 8] = (f16)(acc[nt][rg] + bias);
    }
  } else {
    int i2 = w * 16 + quad * 4;              // token offset within m0 block
    int it2 = (m0 + i2) >> 5;
    int qd2 = (i2 >> 3) & 3;
    int e2 = i2 & 7;                          // 0 or 4; rg appends
#pragma unroll
    for (int nt = 0; nt < 4; nt++) {
      int o = n0 + nt * 16 + col;
      float bias = bcat[o];
      int c = o - 256;
      f16x4v pv;
#pragma unroll
      for (int rg = 0; rg < 4; rg++) pv[rg] = (f16)(acc[nt][rg] + bias);
      size_t addr = (size_t)b * 1048576 + (size_t)(c >> 4) * 65536 +
                    (size_t)it2 * 512 + (size_t)qd2 * 128 + (size_t)(c & 15) * 8 + e2;
      *(f16x4v*)&vT[addr] = pv;
    }
  }
}

// ---------------- kernel 2: row sums of exp(S), register-direct tiled ----------------
// wg = (jblk, ih, b), 512 thr. Wave (ti=w&3, half=w>>2): K j-tile pair
// resident in regs; 32 i-iters, Q frags dbuf-prefetched; exp + in-wave
// j-reduction. partial[b][jblk*2+half][i] = sum of 32 exp. No LDS/barriers.
__global__ void __launch_bounds__(512, 2)
k_rows(const f16* __restrict__ qT, const f16* __restrict__ kT,
       float* __restrict__ partial) {
  int jblk = blockIdx.x, ih = blockIdx.y, b = blockIdx.z;
  int tid = threadIdx.x, l = tid & 63, w = tid >> 6;
  int col = l & 15;
  int ti = w & 3, half = w >> 2, tjb = half * 2;
  const f16* ktb = kT + (size_t)b * 524288 + (size_t)(jblk * 4 + tjb) * 2048 + l * 8;
  const f16* qtb = qT + (size_t)b * 524288 + (size_t)ti * 2048 + l * 8;
  f16x8v ka0[4], ka1[4];
#pragma unroll
  for (int ks = 0; ks < 4; ks++) {
    ka0[ks] = *(const f16x8v*)(ktb + ks * 512);
    ka1[ks] = *(const f16x8v*)(ktb + 2048 + ks * 512);
  }
  float* pout = partial + ((size_t)(b * 64 + jblk) * 2 + half) * 4096 + ti * 16 + col;
  int it0 = ih * 32;
  f16x8v qfA[4], qfB[4];
#pragma unroll
  for (int ks = 0; ks < 4; ks++)
    qfA[ks] = *(const f16x8v*)(qtb + (size_t)it0 * 8192 + ks * 512);

#define ROWS_BODY(IT, QF, QN, PREF)                                           \
  {                                                                           \
    if (PREF) {                                                               \
      _Pragma("unroll") for (int ks = 0; ks < 4; ks++)                        \
        QN[ks] = *(const f16x8v*)(qtb + (size_t)((IT) + 1) * 8192 + ks * 512);\
    }                                                                         \
    f32x4v s0 = {}, s1 = {};                                                  \
    _Pragma("unroll") for (int ks = 0; ks < 4; ks++) {                        \
      s0 = mfma16(ka0[ks], QF[ks], s0);                                       \
      s1 = mfma16(ka1[ks], QF[ks], s1);                                       \
    }                                                                         \
    float t = 0.f;                                                            \
    _Pragma("unroll") for (int rg = 0; rg < 4; rg++)                          \
      t += __expf(s0[rg]) + __expf(s1[rg]);                                   \
    t += __shfl_xor(t, 16);                                                   \
    t += __shfl_xor(t, 32);                                                   \
    if (l < 16) pout[(size_t)(IT) * 64] = t;                                  \
  }

  for (int itp = 0; itp < 16; itp++) {
    int itA = it0 + itp * 2;
    ROWS_BODY(itA, qfA, qfB, true)
    ROWS_BODY(itA + 1, qfB, qfA, itp < 15)
  }
#undef ROWS_BODY
}

// ---------------- kernel 3: combine partials -> rinv = 1/rowsum ----------------
__global__ void k_rsum(const float* __restrict__ partial, float* __restrict__ rinv) {
  int b = blockIdx.y;
  int i = blockIdx.x * 256 + threadIdx.x;
  const float* p = partial + (size_t)b * 128 * 4096 + i;
  float s = 0.f;
#pragma unroll 8
  for (int jb = 0; jb < 128; jb++) s += p[(size_t)jb * 4096];
  rinv[(size_t)b * 4096 + i] = 1.0f / s;
}

// ---------------- kernel 4: fused recompute + AV, register-direct tiled ----------------
// Per wg: batch b, j-cols [j0,j0+64), all 256 c. Loop i in 64-steps:
//   S^T = mfma(K_regs, Q_regs);  E' = exp(S)*rinv -> sE (dbuf, swizzled)
//   acc[c][j] += mfma(V_regs, E'^T)
// All frag loads = coalesced 1KB from tiled layouts, prefetched 1 tile ahead.
// One lgkm-only s_barrier per iter (sE dbuf makes WAR safe — R2-verified).
__global__ void __launch_bounds__(512, 2)
k_fav(const f16* __restrict__ qT, const f16* __restrict__ kT,
      const f16* __restrict__ vT, const float* __restrict__ rinv,
      const float* __restrict__ x, const float* __restrict__ gamma,
      float* __restrict__ out) {
  __shared__ f16 sE[2][4096];   // [buf][64 j][64 i], 8-elem groups XOR(j&7)
  // XCD-chunked swizzle: 256 wgs, 8 XCDs -> contiguous 32-wg slice per XCD.
  int wg = blockIdx.x;
  int lg = (wg & 7) * 32 + (wg >> 3);
  int b = lg >> 6, j0 = (lg & 63) * 64;
  int tid = threadIdx.x, l = tid & 63, w = tid >> 6;
  int col = l & 15, quad = l >> 4;
  int ti = w & 3, tjb = (w >> 2) * 2;
  const f16* ktb = kT + (size_t)b * 524288 + (size_t)(j0 / 16 + tjb) * 2048 + l * 8;
  const f16* qtb = qT + (size_t)b * 524288 + (size_t)ti * 2048 + l * 8;
  const f16* vtb = vT + (size_t)b * 1048576 + (size_t)(w * 2) * 65536 + l * 8;
  const float* rp = rinv + (size_t)b * 4096 + ti * 16 + col;
  // K fragments: resident whole kernel
  f16x8v ka0[4], ka1[4];
#pragma unroll
  for (int ks = 0; ks < 4; ks++) {
    ka0[ks] = *(const f16x8v*)(ktb + ks * 512);
    ka1[ks] = *(const f16x8v*)(ktb + 2048 + ks * 512);
  }
  f16x8v qfA[4], qfB[4], vfA[2][2], vfB[2][2];
  float rvA, rvB;
#pragma unroll
  for (int ks = 0; ks < 4; ks++) qfA[ks] = *(const f16x8v*)(qtb + ks * 512);
#pragma unroll
  for (int mt = 0; mt < 2; mt++)
#pragma unroll
    for (int ks = 0; ks < 2; ks++)
      vfA[mt][ks] = *(const f16x8v*)(vtb + mt * 65536 + ks * 512);
  rvA = rp[0];
  f32x4v acc[2][4] = {};
  int ig = ti * 2 + (col >> 3);
  int i_lo = col & 7;

#define FAV_BODY(IT, QF, VF, RV, QN, VN, RN, PREF, SEB)                        \
  {                                                                            \
    if (PREF) {                                                                \
      _Pragma("unroll") for (int ks = 0; ks < 4; ks++)                         \
        QN[ks] = *(const f16x8v*)(qtb + (size_t)((IT) + 1) * 8192 + ks * 512); \
      _Pragma("unroll") for (int mt = 0; mt < 2; mt++)                         \
        _Pragma("unroll") for (int ks = 0; ks < 2; ks++)                       \
          VN[mt][ks] = *(const f16x8v*)(vtb + mt * 65536 +                     \
                                        (size_t)(((IT) + 1) * 2 + ks) * 512);  \
      RN = rp[((IT) + 1) * 64];                                                \
    }                                                                          \
    f32x4v s0 = {}, s1 = {};                                                   \
    _Pragma("unroll") for (int ks = 0; ks < 4; ks++) {                         \
      s0 = mfma16(ka0[ks], QF[ks], s0);                                        \
      s1 = mfma16(ka1[ks], QF[ks], s1);                                        \
    }                                                                          \
    _Pragma("unroll") for (int rg = 0; rg < 4; rg++) {                         \
      int jl0 = tjb * 16 + quad * 4 + rg;                                      \
      sE[SEB][jl0 * 64 + ((ig ^ (jl0 & 7)) * 8) + i_lo] = (f16)(__expf(s0[rg]) * RV); \
      sE[SEB][(jl0 + 16) * 64 + ((ig ^ (jl0 & 7)) * 8) + i_lo] = (f16)(__expf(s1[rg]) * RV); \
    }                                                                          \
    asm volatile("s_waitcnt lgkmcnt(0)\n\ts_barrier" ::: "memory");            \
    _Pragma("unroll") for (int ks = 0; ks < 2; ks++) {                         \
      int sw = ((ks * 4 + quad) ^ (col & 7)) * 8;                              \
      f16x8v e0 = *(const f16x8v*)&sE[SEB][col * 64 + sw];                     \
      f16x8v e1 = *(const f16x8v*)&sE[SEB][(16 + col) * 64 + sw];              \
      f16x8v e2 = *(const f16x8v*)&sE[SEB][(32 + col) * 64 + sw];              \
      f16x8v e3 = *(const f16x8v*)&sE[SEB][(48 + col) * 64 + sw];              \
      acc[0][0] = mfma16(VF[0][ks], e0, acc[0][0]);                            \
      acc[0][1] = mfma16(VF[0][ks], e1, acc[0][1]);                            \
      acc[0][2] = mfma16(VF[0][ks], e2, acc[0][2]);                            \
      acc[0][3] = mfma16(VF[0][ks], e3, acc[0][3]);                            \
      acc[1][0] = mfma16(VF[1][ks], e0, acc[1][0]);                            \
      acc[1][1] = mfma16(VF[1][ks], e1, acc[1][1]);                            \
      acc[1][2] = mfma16(VF[1][ks], e2, acc[1][2]);                            \
      acc[1][3] = mfma16(VF[1][ks], e3, acc[1][3]);                            \
    }                                                                          \
  }

  for (int itp = 0; itp < 32; itp++) {
    int itA = itp * 2;
    FAV_BODY(itA, qfA, vfA, rvA, qfB, vfB, rvB, true, 0)
    FAV_BODY(itA + 1, qfB, vfB, rvB, qfA, vfA, rvA, itp < 31, 1)
  }
#undef FAV_BODY

  float gm = gamma[0];
  const float* xb = x + (size_t)b * 256 * 4096;
  float* ob = out + (size_t)b * 256 * 4096;
#pragma unroll
  for (int mt = 0; mt < 2; mt++)
#pragma unroll
    for (int jt = 0; jt < 4; jt++) {
      int c = w * 32 + mt * 16 + quad * 4;
      int j = j0 + jt * 16 + col;
#pragma unroll
      for (int rg = 0; rg < 4; rg++) {
        size_t off = (size_t)(c + rg) * 4096 + j;
        ob[off] = gm * acc[mt][jt][rg] + xb[off];
      }
    }
}

extern "C" void kernel_launch(void* const* d_in, const int* in_sizes, int n_in,
                              void* d_out, int out_size, void* d_ws, size_t ws_size,
                              hipStream_t stream) {
  (void)in_sizes; (void)n_in; (void)out_size; (void)ws_size;
  const float* x  = (const float*)d_in[0];
  const float* wq = (const float*)d_in[1];
  const float* bq = (const float*)d_in[2];
  const float* wk = (const float*)d_in[3];
  const float* bk = (const float*)d_in[4];
  const float* wv = (const float*)d_in[5];
  const float* bv = (const float*)d_in[6];
  const float* gm = (const float*)d_in[7];
  float* out = (float*)d_out;

  char* ws = (char*)d_ws;
  f16*  xh = (f16*)ws;                          // 8 MB
  f16*  qT = (f16*)(ws + 8388608);              // 4 MB fragment-tiled Q
  f16*  kT = (f16*)(ws + 12582912);             // 4 MB fragment-tiled K
  f16*  vT = (f16*)(ws + 16777216);             // 8 MB fragment-tiled V
  f16*  wh = (f16*)(ws + 25165824);             // 256 KB
  float* bcat    = (float*)(ws + 25427968);     // 2 KB
  float* rinv    = (float*)(ws + 25430016);     // 64 KB
  float* partial = (float*)(ws + 25495552);     // 8 MB: [b][128][4096]

  hipLaunchKernelGGL(k_wcvt, dim3(512), dim3(256), 0, stream, wq, bq, wk, bk, wv, bv, wh, bcat);
  hipLaunchKernelGGL(k_xsplit, dim3(64, 4, 4), dim3(256), 0, stream, x, xh);
  hipLaunchKernelGGL(k_proj, dim3(8, 64, 4), dim3(256), 65536, stream, xh, wh, bcat, qT, kT, vT);
  hipLaunchKernelGGL(k_rows, dim3(64, 2, 4), dim3(512), 0, stream, qT, kT, partial);
  hipLaunchKernelGGL(k_rsum, dim3(16, 4), dim3(256), 0, stream, partial, rinv);
  hipLaunchKernelGGL(k_fav, dim3(256), dim3(512), 0, stream, qT, kT, vT, rinv, x, gm, out);
}